// Round 5
// baseline (103.529 us; speedup 1.0000x reference)
//
#include <hip/hip_runtime.h>

// RelationalDense: out[n,:] = feat[n,:] @ W[rel[n]] + bias,  W = einsum('rb,bfo', lin, V)
// N=65536, F=64, U=64, R=25, B=8.
//
// Buckets rows by relation so every wave is relation-uniform -> W reads are
// wave-uniform scalar (SMEM) broadcasts, not 23-way cacheline gathers.
// R5: k_main was TA/L1 line-address bound (~22 us): every feature load instr
// touched 64 scattered lines, re-read by all 4 quarter-waves (8.2M line-cycles).
// Fix: stage 64 rows (16 KB) in LDS once per block with 4-lanes-per-row loads
// (16 lines/instr, loaded once) -> feature line traffic drops 16x; compute
// reads LDS (stride 17*v4f: lane-advance 4 banks = min-phase, conflict-free).

typedef float v4f __attribute__((ext_vector_type(4)));

#define NN 65536
#define FF 64
#define UU 64
#define RR 25
#define BB 8
#define CAP 4096                 // slots per bucket; mean fill 2621, +29 sigma safe
#define NSLOT (RR * CAP)         // 102400

// ws layout:
//   [0, NSLOT*4)           idx_sorted (int)  -- NOT memset; validity = pos < cnt
//   [NSLOT*4, +128)        cursors (25 ints), memset 0; == bucket counts after k_prep
//   [W_OFF, +R*F*U*4)      W fp32
#define IDX_OFF 0
#define CUR_OFF (NSLOT * 4)
#define W_OFF   (NSLOT * 4 + 128)
#define WS_NEED ((size_t)(W_OFF + RR * FF * UU * 4))

// ---------------------------------------------------------------------------
// K1: fused W precompute (blocks [0,400)) + bucket scatter (blocks [400,656))
// ---------------------------------------------------------------------------
__global__ __launch_bounds__(256) void k_prep(
    const float* __restrict__ kern,   // [B,F,U]
    const float* __restrict__ lin,    // [R,B]
    const int*   __restrict__ rel,    // [N]
    float*       __restrict__ W,      // [R,F,U]
    int*         __restrict__ idx_sorted,
    int*         __restrict__ cursors) {
  const int wblocks = (RR * FF * UU) / 256;  // 400
  int bid = blockIdx.x;
  if (bid < wblocks) {
    int idx = bid * 256 + threadIdx.x;
    int r  = __builtin_amdgcn_readfirstlane(idx >> 12);
    int fo = idx & (FF * UU - 1);
    float acc = 0.f;
#pragma unroll
    for (int b = 0; b < BB; ++b)
      acc += lin[r * BB + b] * kern[b * (FF * UU) + fo];
    W[idx] = acc;
  } else {
    // scatter: block of 256 rows -> LDS histogram -> reserve global range -> place
    int sb  = bid - wblocks;
    int tid = threadIdx.x;
    __shared__ int cnt[RR], base[RR], lcur[RR];
    if (tid < RR) { cnt[tid] = 0; lcur[tid] = 0; }
    __syncthreads();
    int row = sb * 256 + tid;
    int r = rel[row];
    atomicAdd(&cnt[r], 1);
    __syncthreads();
    if (tid < RR) base[tid] = atomicAdd(&cursors[tid], cnt[tid]);
    __syncthreads();
    int loc = atomicAdd(&lcur[r], 1);
    idx_sorted[r * CAP + base[r] + loc] = row;
  }
}

// ---------------------------------------------------------------------------
// K2: main compute. Block 256 = 4 waves over the SAME 64 slots; wave w is
// output quarter q=w (uniform) -> W/bias scalarize to s_load broadcasts.
// Features staged to LDS once per block: iter i, thread t loads row (s>>4),
// seg (s&15), s=i*256+t -> 4 lanes/row/line -> 16 lines per instr.
// LDS row stride 17 v4f (68 dwords): lane-to-lane bank advance 4 -> min-phase.
// ---------------------------------------------------------------------------
__global__ __launch_bounds__(256, 4) void k_main(
    const float* __restrict__ features,  // [N,F]
    const float* __restrict__ bias,      // [U]
    const float* __restrict__ W,         // [R,F,U]
    const int*   __restrict__ idx_sorted,
    const int*   __restrict__ cursors,   // bucket counts after k_prep
    float*       __restrict__ out) {     // [N,U]
  __shared__ int srow[64];
  __shared__ v4f sfeat[64][17];          // 17408 B; pad breaks 256B-stride banks

  int tid       = threadIdx.x;
  int base_slot = blockIdx.x * 64;
  int r   = __builtin_amdgcn_readfirstlane(base_slot >> 12);  // uniform (CAP%64==0)
  int cnt = cursors[r];                                       // uniform -> s_load

  if (tid < 64) {
    int slot = base_slot + tid;
    srow[tid] = ((slot & (CAP - 1)) < cnt) ? idx_sorted[slot] : -1;
  }
  __syncthreads();

  const v4f* f4 = reinterpret_cast<const v4f*>(features);
#pragma unroll
  for (int i = 0; i < 4; ++i) {          // 1024 segments of 16B, 4 per thread
    int s   = i * 256 + tid;
    int rl  = s >> 4;                    // local row 0..63
    int seg = s & 15;
    int row = srow[rl];
    if (row >= 0)
      sfeat[rl][seg] = f4[(size_t)row * 16 + seg];
  }
  __syncthreads();

  int lane = tid & 63;
  int q    = __builtin_amdgcn_readfirstlane(tid >> 6);  // 0..3 uniform per wave
  int row  = srow[lane];
  if (row < 0) return;                   // after all syncs -- safe

  const float* Wq = W + r * (FF * UU) + q * 16;         // uniform -> SMEM

  float acc[16];
#pragma unroll
  for (int j = 0; j < 16; ++j) acc[j] = bias[q * 16 + j];  // uniform -> s_load

#pragma unroll
  for (int ch = 0; ch < 4; ++ch) {       // 16 features per chunk
    v4f fv[4];
#pragma unroll
    for (int k = 0; k < 4; ++k) fv[k] = sfeat[lane][ch * 4 + k];  // ds_read_b128
#pragma unroll
    for (int k = 0; k < 4; ++k) {
#pragma unroll
      for (int c = 0; c < 4; ++c) {
        int f = ch * 16 + k * 4 + c;
        float fs = fv[k][c];
#pragma unroll
        for (int j = 0; j < 16; ++j)
          acc[j] += fs * Wq[f * UU + j]; // v_fmac, SGPR W operand
      }
    }
  }

  v4f* o4 = reinterpret_cast<v4f*>(out + (size_t)row * UU + q * 16);
#pragma unroll
  for (int j4 = 0; j4 < 4; ++j4) {
    v4f v = {acc[4 * j4], acc[4 * j4 + 1], acc[4 * j4 + 2], acc[4 * j4 + 3]};
    o4[j4] = v;
  }
}

// ---------------------------------------------------------------------------
// Fallback (no workspace): compute W_r on the fly per row. Safety net only.
// ---------------------------------------------------------------------------
__global__ __launch_bounds__(256) void k_fallback(
    const float* __restrict__ features,
    const int*   __restrict__ rel,
    const float* __restrict__ kern,
    const float* __restrict__ lin,
    const float* __restrict__ bias,
    float*       __restrict__ out) {
  int tid = threadIdx.x;
  int row = blockIdx.x * 64 + (tid & 63);
  int q   = __builtin_amdgcn_readfirstlane(tid >> 6);
  int r   = rel[row];
  float cf[BB];
#pragma unroll
  for (int b = 0; b < BB; ++b) cf[b] = lin[r * BB + b];
  const v4f* fr = reinterpret_cast<const v4f*>(features + (size_t)row * FF);
  float acc[16];
#pragma unroll
  for (int j = 0; j < 16; ++j) acc[j] = bias[q * 16 + j];
#pragma unroll
  for (int ch = 0; ch < 4; ++ch) {
    v4f fv[4];
#pragma unroll
    for (int k = 0; k < 4; ++k) fv[k] = fr[ch * 4 + k];
#pragma unroll
    for (int k = 0; k < 4; ++k) {
#pragma unroll
      for (int c = 0; c < 4; ++c) {
        int f = ch * 16 + k * 4 + c;
        float fs = fv[k][c];
        float wf[16];
#pragma unroll
        for (int j = 0; j < 16; ++j) wf[j] = 0.f;
#pragma unroll
        for (int b = 0; b < BB; ++b) {
          const float* Vb = kern + b * (FF * UU) + f * UU + q * 16;
#pragma unroll
          for (int j = 0; j < 16; ++j) wf[j] += cf[b] * Vb[j];
        }
#pragma unroll
        for (int j = 0; j < 16; ++j) acc[j] += fs * wf[j];
      }
    }
  }
  v4f* o4 = reinterpret_cast<v4f*>(out + (size_t)row * UU + q * 16);
#pragma unroll
  for (int j4 = 0; j4 < 4; ++j4) {
    v4f v = {acc[4 * j4], acc[4 * j4 + 1], acc[4 * j4 + 2], acc[4 * j4 + 3]};
    o4[j4] = v;
  }
}

extern "C" void kernel_launch(void* const* d_in, const int* in_sizes, int n_in,
                              void* d_out, int out_size, void* d_ws, size_t ws_size,
                              hipStream_t stream) {
  const float* features  = (const float*)d_in[0];
  const int*   relations = (const int*)d_in[1];
  const float* kern      = (const float*)d_in[2];
  const float* lin       = (const float*)d_in[3];
  const float* bias      = (const float*)d_in[4];
  float* out = (float*)d_out;

  if (ws_size >= WS_NEED) {
    char*  ws         = (char*)d_ws;
    int*   idx_sorted = (int*)(ws + IDX_OFF);
    int*   cursors    = (int*)(ws + CUR_OFF);
    float* W          = (float*)(ws + W_OFF);
    (void)hipMemsetAsync(cursors, 0, RR * sizeof(int), stream);   // 100 B only
    k_prep<<<(RR * FF * UU) / 256 + NN / 256, 256, 0, stream>>>(
        kern, lin, relations, W, idx_sorted, cursors);
    k_main<<<NSLOT / 64, 256, 0, stream>>>(features, bias, W, idx_sorted, cursors, out);
  } else {
    k_fallback<<<NN / 64, 256, 0, stream>>>(features, relations, kern, lin, bias, out);
  }
}